// Round 1
// baseline (288.485 us; speedup 1.0000x reference)
//
#include <hip/hip_runtime.h>
#include <hip/hip_bf16.h>

// LFA_self: fused (proj -> MHA over 49 tokens -> proj) for MI355X.
// Key algebra: scores = Xq (Wq Wk^T) Xk^T summed over the head's 64 spatial
// positions; out = (attn . Xv) (Wv Wo) + bv Wo + bo. Head h = contiguous
// 1024-float slice per token. One block per (b,h): 512 blocks = 2/CU.

#define NT 49            // tokens
#define TOKS 16384       // floats per (b,t)
#define HSL 1024         // floats per head slice

typedef __attribute__((ext_vector_type(8))) short bf16x8;
typedef __attribute__((ext_vector_type(4))) float f32x4;

__device__ __forceinline__ ushort f2bf(float f) {
    union { float f; unsigned u; } v; v.f = f;
    return (ushort)((v.u + 0x7fffu + ((v.u >> 16) & 1u)) >> 16);   // RNE
}

__global__ __launch_bounds__(256, 2) void lfa_fused(
    const float* __restrict__ vin, const float* __restrict__ kin,
    const float* __restrict__ qin,
    const float* __restrict__ Wq, const float* __restrict__ bq,
    const float* __restrict__ Wk, const float* __restrict__ bk,
    const float* __restrict__ Wv, const float* __restrict__ bv,
    const float* __restrict__ Wo, const float* __restrict__ bo,
    float* __restrict__ out, float* __restrict__ attn)
{
    // LDS budget 56.7KB -> 2 blocks/CU.
    __shared__ ushort bufA[64*128];   // Yq bf16, 256B rows, XOR-swizzled
    __shared__ ushort bufB[64*128];   // Xk (256B rows) / Xv (128B rows)
    __shared__ ushort aT[64*64];      // attn bf16 [t][t2], 128B rows, swizzled
    __shared__ float  big[NT*68];     // scores / V~ staging, padded stride 68
    __shared__ float  Msh[256];       // Wq Wk^T
    __shared__ float  WvoSh[256];     // Wv Wo
    __shared__ float  bvoSh[16];      // bv Wo + bo
    __shared__ float  wkbqSh[16];     // Wk bq (score bias along t2; 0 here)
    __shared__ float  gSh[NT];
    __shared__ int    flagSh;

    const int tid  = threadIdx.x;
    const int lane = tid & 63;
    const int wv   = tid >> 6;
    const int b    = blockIdx.x >> 4;
    const int h    = blockIdx.x & 15;

    const float* qbase = qin + (size_t)b * NT * TOKS + h * HSL;
    const float* kbase = kin + (size_t)b * NT * TOKS + h * HSL;
    const float* vbase = vin + (size_t)b * NT * TOKS + h * HSL;

    // ---- init: zero LDS pads (rows 49..63 must be 0 for MFMA), weight products
    {
        unsigned* z0 = (unsigned*)bufA;
        unsigned* z1 = (unsigned*)bufB;
        unsigned* z2 = (unsigned*)aT;
        for (int i = tid; i < 4096; i += 256) { z0[i] = 0u; z1[i] = 0u; }
        for (int i = tid; i < 2048; i += 256) z2[i] = 0u;

        int c1 = tid >> 4, c2 = tid & 15;
        float m = 0.f, wvo = 0.f;
        #pragma unroll
        for (int f = 0; f < 16; ++f) {
            m   += Wq[c1*16+f] * Wk[c2*16+f];
            wvo += Wv[c1*16+f] * Wo[f*16+c2];
        }
        Msh[tid]   = m;
        WvoSh[tid] = wvo;
        if (tid < 16) {
            float s = 0.f, wb = 0.f;
            #pragma unroll
            for (int g = 0; g < 16; ++g) { s += bv[g]*Wo[g*16+tid]; wb += Wk[tid*16+g]*bq[g]; }
            bvoSh[tid]  = s + bo[tid];
            wkbqSh[tid] = wb;
        }
        if (tid < NT) gSh[tid] = 0.f;
        if (tid == 0) flagSh = 0;
    }
    __syncthreads();
    if (tid < 16 && wkbqSh[tid] != 0.f) flagSh = 1;   // benign race
    __syncthreads();
    const int hasbq = flagSh;

    // ================= phase 1: scores S[49][49], K=1024 in 8 chunks of 128
    f32x4 accS[4];
    #pragma unroll
    for (int nt = 0; nt < 4; ++nt) accS[nt] = (f32x4){0.f,0.f,0.f,0.f};

    for (int kc = 0; kc < 8; ++kc) {
        // stage Yq = Xq*M (tasks 0..391) and Xk (tasks 392..783); 16 floats/task
        for (int idx = tid; idx < 784; idx += 256) {
            const int isK = idx >= 392;
            const int p   = isK ? idx - 392 : idx;
            const int t   = p >> 3, si = p & 7;
            const float* src = (isK ? kbase : qbase) + (size_t)t*TOKS + (kc*8 + si)*16;
            float x[16];
            *(float4*)(x)     = *(const float4*)(src);
            *(float4*)(x + 4) = *(const float4*)(src + 4);
            *(float4*)(x + 8) = *(const float4*)(src + 8);
            *(float4*)(x +12) = *(const float4*)(src +12);
            unsigned wpk[8];
            if (!isK) {
                #pragma unroll
                for (int c2 = 0; c2 < 16; c2 += 2) {
                    float y0 = 0.f, y1 = 0.f;
                    #pragma unroll
                    for (int c = 0; c < 16; ++c) {
                        y0 += x[c] * Msh[c*16 + c2];
                        y1 += x[c] * Msh[c*16 + c2 + 1];
                    }
                    wpk[c2 >> 1] = (unsigned)f2bf(y0) | ((unsigned)f2bf(y1) << 16);
                }
                const int bo_ = t*256 + si*32, sw = (t & 7) << 4;
                *(uint4*)((char*)bufA + ((bo_     ) ^ sw)) = *(uint4*)(wpk);
                *(uint4*)((char*)bufA + ((bo_ + 16) ^ sw)) = *(uint4*)(wpk + 4);
            } else {
                #pragma unroll
                for (int c = 0; c < 16; c += 2)
                    wpk[c >> 1] = (unsigned)f2bf(x[c]) | ((unsigned)f2bf(x[c+1]) << 16);
                const int bo_ = t*256 + si*32, sw = (t & 7) << 4;
                *(uint4*)((char*)bufB + ((bo_     ) ^ sw)) = *(uint4*)(wpk);
                *(uint4*)((char*)bufB + ((bo_ + 16) ^ sw)) = *(uint4*)(wpk + 4);
                if (hasbq) {
                    float pg = 0.f;
                    #pragma unroll
                    for (int c = 0; c < 16; ++c) pg += x[c] * wkbqSh[c];
                    atomicAdd(&gSh[t], pg);
                }
            }
        }
        __syncthreads();
        // MFMA: wave wv owns M-tile wv; 4 N-tiles; K-chunk 128 = 4 ksteps
        #pragma unroll
        for (int ks = 0; ks < 4; ++ks) {
            const int ra  = wv*16 + (lane & 15);
            const int abo = (ra*256 + (ks*32 + (lane >> 4)*8)*2) ^ ((ra & 7) << 4);
            const bf16x8 af = *(const bf16x8*)((const char*)bufA + abo);
            #pragma unroll
            for (int nt = 0; nt < 4; ++nt) {
                const int rb  = nt*16 + (lane & 15);
                const int bbo = (rb*256 + (ks*32 + (lane >> 4)*8)*2) ^ ((rb & 7) << 4);
                const bf16x8 bf = *(const bf16x8*)((const char*)bufB + bbo);
                accS[nt] = __builtin_amdgcn_mfma_f32_16x16x32_bf16(af, bf, accS[nt], 0, 0, 0);
            }
        }
        __syncthreads();
    }

    // write scores to big (scale 1/sqrt(1024), + g(t2) bias term)
    #pragma unroll
    for (int nt = 0; nt < 4; ++nt) {
        const int col = nt*16 + (lane & 15);
        #pragma unroll
        for (int r = 0; r < 4; ++r) {
            const int row = wv*16 + (lane >> 4)*4 + r;
            if (row < NT) {
                const float gv = (col < NT) ? gSh[col] : 0.f;
                big[row*68 + col] = (accS[nt][r] + gv) * 0.03125f;
            }
        }
    }
    __syncthreads();

    // softmax (one row per thread; 49 rows) -> big holds attn fp32; aT bf16
    if (tid < NT) {
        float mx = -1e30f;
        for (int j = 0; j < NT; ++j) mx = fmaxf(mx, big[tid*68 + j]);
        float s = 0.f;
        for (int j = 0; j < NT; ++j) {
            const float e = __expf(big[tid*68 + j] - mx);
            big[tid*68 + j] = e; s += e;
        }
        const float inv = 1.0f / s;
        for (int j = 0; j < NT; ++j) {
            const float a = big[tid*68 + j] * inv;
            big[tid*68 + j] = a;
            const int bo_ = (tid*128 + j*2) ^ ((tid & 7) << 4);
            *(ushort*)((char*)aT + bo_) = f2bf(a);
        }
    }
    __syncthreads();

    // attn output (fp32, coalesced)
    {
        float* attnb = attn + (size_t)blockIdx.x * (NT * NT);
        for (int i = tid; i < NT*NT; i += 256) {
            const int t = i / NT, j = i - t*NT;
            attnb[i] = big[t*68 + j];
        }
    }
    __syncthreads();

    // ================= phase 3: V~ = attn . Xv, then out = V~ Wvo + bvo
    // 16 chunks of 64 d-columns; bufB reused with 128B rows
    for (int kc = 0; kc < 16; ++kc) {
        for (int p = tid; p < 196; p += 256) {
            const int t = p >> 2, si = p & 3;
            const float* src = vbase + (size_t)t*TOKS + (kc*4 + si)*16;
            float x[16];
            *(float4*)(x)     = *(const float4*)(src);
            *(float4*)(x + 4) = *(const float4*)(src + 4);
            *(float4*)(x + 8) = *(const float4*)(src + 8);
            *(float4*)(x +12) = *(const float4*)(src +12);
            unsigned wpk[8];
            #pragma unroll
            for (int c = 0; c < 16; c += 2)
                wpk[c >> 1] = (unsigned)f2bf(x[c]) | ((unsigned)f2bf(x[c+1]) << 16);
            const int bo_ = t*128 + si*32, sw = (t & 7) << 4;
            *(uint4*)((char*)bufB + ((bo_     ) ^ sw)) = *(uint4*)(wpk);
            *(uint4*)((char*)bufB + ((bo_ + 16) ^ sw)) = *(uint4*)(wpk + 4);
        }
        __syncthreads();

        f32x4 accV[4];
        #pragma unroll
        for (int mt = 0; mt < 4; ++mt) accV[mt] = (f32x4){0.f,0.f,0.f,0.f};
        const int n = wv*16 + (lane & 15);      // wave wv owns N-tile wv
        #pragma unroll
        for (int ks = 0; ks < 2; ++ks) {
            bf16x8 bf;
            #pragma unroll
            for (int j = 0; j < 8; ++j) {       // u16 gather: B[k=t2][n=d]
                const int r   = ks*32 + (lane >> 4)*8 + j;
                const int bo_ = (r*128 + n*2) ^ ((r & 7) << 4);
                bf[j] = *(const short*)((const char*)bufB + bo_);
            }
            #pragma unroll
            for (int mt = 0; mt < 4; ++mt) {
                const int ra  = mt*16 + (lane & 15);
                const int abo = (ra*128 + (ks*32 + (lane >> 4)*8)*2) ^ ((ra & 7) << 4);
                const bf16x8 af = *(const bf16x8*)((const char*)aT + abo);
                accV[mt] = __builtin_amdgcn_mfma_f32_16x16x32_bf16(af, bf, accV[mt], 0, 0, 0);
            }
        }
        #pragma unroll
        for (int mt = 0; mt < 4; ++mt) {
            #pragma unroll
            for (int r = 0; r < 4; ++r) {
                const int row = mt*16 + (lane >> 4)*4 + r;
                if (row < NT) big[row*68 + n] = accV[mt][r];
            }
        }
        __syncthreads();

        // epilogue: out = V~ * Wvo + bvo  (16 fp32 per position)
        for (int p = tid; p < 196; p += 256) {
            const int t = p >> 2, si = p & 3;
            float vv[16];
            *(float4*)(vv)     = *(float4*)&big[t*68 + si*16];
            *(float4*)(vv + 4) = *(float4*)&big[t*68 + si*16 + 4];
            *(float4*)(vv + 8) = *(float4*)&big[t*68 + si*16 + 8];
            *(float4*)(vv +12) = *(float4*)&big[t*68 + si*16 +12];
            float o[16];
            #pragma unroll
            for (int f2 = 0; f2 < 16; ++f2) {
                float s = bvoSh[f2];
                #pragma unroll
                for (int f = 0; f < 16; ++f) s += vv[f] * WvoSh[f*16 + f2];
                o[f2] = s;
            }
            float* dst = out + (size_t)(b*NT + t)*TOKS + h*HSL + (kc*4 + si)*16;
            *(float4*)(dst)     = *(float4*)(o);
            *(float4*)(dst + 4) = *(float4*)(o + 4);
            *(float4*)(dst + 8) = *(float4*)(o + 8);
            *(float4*)(dst +12) = *(float4*)(o +12);
        }
        __syncthreads();
    }
}

extern "C" void kernel_launch(void* const* d_in, const int* in_sizes, int n_in,
                              void* d_out, int out_size, void* d_ws, size_t ws_size,
                              hipStream_t stream) {
    const float* v  = (const float*)d_in[0];
    const float* k  = (const float*)d_in[1];
    const float* q  = (const float*)d_in[2];
    const float* Wq = (const float*)d_in[3];
    const float* bq = (const float*)d_in[4];
    const float* Wk = (const float*)d_in[5];
    const float* bk = (const float*)d_in[6];   // softmax-row-invariant; unused
    const float* Wv = (const float*)d_in[7];
    const float* bv = (const float*)d_in[8];
    const float* Wo = (const float*)d_in[9];
    const float* bo = (const float*)d_in[10];
    (void)bk; (void)in_sizes; (void)n_in; (void)d_ws; (void)ws_size;

    float* outp  = (float*)d_out;
    float* attnp = outp + (size_t)32 * 49 * 16384;   // out | attn concat
    (void)out_size;

    lfa_fused<<<dim3(512), dim3(256), 0, stream>>>(
        v, k, q, Wq, bq, Wk, bk, Wv, bv, Wo, bo, outp, attnp);
}